// Round 9
// baseline (199.922 us; speedup 1.0000x reference)
//
#include <hip/hip_runtime.h>
#include <cstdint>
#include <cstddef>

#define NEGV -1e9f

typedef __bf16 bf16x8 __attribute__((ext_vector_type(8)));
typedef float f32x4 __attribute__((ext_vector_type(4)));
typedef unsigned short us4 __attribute__((ext_vector_type(4)));
typedef unsigned short us8 __attribute__((ext_vector_type(8)));

__device__ __forceinline__ unsigned short f2bf(float f) {
  unsigned int u = __float_as_uint(f);
  u += 0x7fffu + ((u >> 16) & 1u);   // round-to-nearest-even
  return (unsigned short)(u >> 16);
}
__device__ __forceinline__ float bf2f(unsigned short u) {
  return __uint_as_float(((unsigned)u) << 16);
}

// async 16B global -> LDS (dest = wave-uniform base + lane*16)
__device__ __forceinline__ void gld16(const void* g, void* l) {
  __builtin_amdgcn_global_load_lds(
      (const __attribute__((address_space(1))) unsigned int*)g,
      (__attribute__((address_space(3))) unsigned int*)l, 16, 0, 0);
}

// ===========================================================================
// Fragment-order layouts (16x16x32 MFMA, lane = hi*16+lo, hi=lane>>4, lo=lane&15):
//  A-frag table  AF[it][kt][lane][c]  : value(i = it*16+lo, j = kt*32+hi*8+c)
//  B-frag table  BF[b][kt][dt][lane][c]: value(d = dt*16+lo, j = kt*32+hi*8+c)
//  C-frag table  CF[b][it][dt][lane][r]: value(i = it*16+hi*4+r, d = dt*16+lo)
// Each (it,kt) / (kt,dt) chunk is 1024 B lane-contiguous -> one gld16 stages it.
// ===========================================================================

// ---------------------------------------------------------------------------
// prep: out_init (0..63) + wcvt 8 weights (64..191) + plain epb/epbT (192..447)
// ---------------------------------------------------------------------------
__global__ void prep_kernel(const float* __restrict__ w0, const float* __restrict__ w1,
                            const float* __restrict__ w2, const float* __restrict__ w3,
                            const float* __restrict__ w4, const float* __restrict__ w5,
                            const float* __restrict__ w6, const float* __restrict__ w7,
                            unsigned short* __restrict__ Wbf,
                            const float* __restrict__ pb,
                            unsigned short* __restrict__ epb,
                            unsigned short* __restrict__ epbT,
                            unsigned int* __restrict__ outEnc) {
  __shared__ unsigned short t[32][33];
  const int blk = blockIdx.x, tid = threadIdx.x;
  if (blk < 64) {
    outEnc[blk * 256 + tid] = 0u;
    return;
  }
  if (blk < 192) {
    const float* Ws[8] = {w0, w1, w2, w3, w4, w5, w6, w7};
    int idx = (blk - 64) * 256 + tid;        // 0..32767 float4s
    int mat = idx >> 12, off = idx & 4095;
    float4 v = *(const float4*)&Ws[mat][(size_t)off * 4];
    us4 p;
    p.x = f2bf(v.x); p.y = f2bf(v.y); p.z = f2bf(v.z); p.w = f2bf(v.w);
    *(us4*)&Wbf[(size_t)mat * 16384 + (size_t)off * 4] = p;
    return;
  }
  const int bid = blk - 192;
  const int j0 = (bid & 31) * 32, i0 = (bid >> 5) * 32;
  const int tx = tid & 31, ty = tid >> 5;
#pragma unroll
  for (int r = 0; r < 4; ++r) {
    int i = i0 + ty + r * 8;
    unsigned short u = f2bf(__expf(pb[(size_t)i * 1024 + j0 + tx]));
    epb[(size_t)i * 1024 + j0 + tx] = u;
    t[ty + r * 8][tx] = u;
  }
  __syncthreads();
#pragma unroll
  for (int r = 0; r < 4; ++r)
    epbT[(size_t)(j0 + ty + r * 8) * 256 + i0 + tx] = t[tx][ty + r * 8];
}

// ---------------------------------------------------------------------------
// proj3_all (256 thr, R6-proven form): blocks [0,256) drug, [256,1280) protein
// projections; [1280,1536) pack epb/epbT into A-frag tables.
// Writes sigQ in C-frag order, eK/eKV in B-frag order, from MFMA accumulators.
// ---------------------------------------------------------------------------
__global__ __launch_bounds__(256) void proj3_all(
    const float* __restrict__ smiles, const float* __restrict__ prot,
    const int* __restrict__ smask, const int* __restrict__ pmask,
    const unsigned short* __restrict__ Wbf,
    const float* __restrict__ bqd, const float* __restrict__ bkd, const float* __restrict__ bvd,
    const float* __restrict__ bqp, const float* __restrict__ bkp, const float* __restrict__ bvp,
    const unsigned short* __restrict__ epb, const unsigned short* __restrict__ epbT,
    unsigned short* __restrict__ AFd, unsigned short* __restrict__ AFp,
    unsigned short* __restrict__ SQd, unsigned short* __restrict__ BKd,
    unsigned short* __restrict__ BVd,
    unsigned short* __restrict__ SQp, unsigned short* __restrict__ BKp,
    unsigned short* __restrict__ BVp) {
  const int tid = threadIdx.x;

  if (blockIdx.x >= 1280) {   // ---- A-frag packing ----
    int sid = (blockIdx.x - 1280) * 256 + tid;   // 0..65535 us8-slots
    if (sid < 32768) {        // drug-query A: [it<16][kt<32][lane][8]
      int lane = sid & 63, kt = (sid >> 6) & 31, it = sid >> 11;
      int i = it * 16 + (lane & 15), j = kt * 32 + (lane >> 4) * 8;
      *(us8*)&AFd[(size_t)sid * 8] = *(const us8*)&epb[(size_t)i * 1024 + j];
    } else {                  // protein-query A: [it<64][kt<8][lane][8]
      int s2 = sid - 32768;
      int lane = s2 & 63, kt = (s2 >> 6) & 7, it = s2 >> 9;
      int i = it * 16 + (lane & 15), j = kt * 32 + (lane >> 4) * 8;
      *(us8*)&AFp[(size_t)s2 * 8] = *(const us8*)&epbT[(size_t)i * 256 + j];
    }
    return;
  }

  __shared__ unsigned short xL[64 * 136];   // 17408 B

  const float* X; const int* mask;
  const unsigned short *Wq, *Wk, *Wv;
  const float *bq, *bk_, *bv;
  unsigned short *SQ, *BK, *BV;
  int T, g0;
  if (blockIdx.x < 256) {
    X = smiles; mask = smask; T = 256; g0 = blockIdx.x * 64;
    Wq = Wbf; Wk = Wbf + 16384; Wv = Wbf + 32768;
    bq = bqd; bk_ = bkd; bv = bvd;
    SQ = SQd; BK = BKd; BV = BVd;
  } else {
    X = prot; mask = pmask; T = 1024; g0 = (blockIdx.x - 256) * 64;
    Wq = Wbf + 3 * 16384; Wk = Wbf + 4 * 16384; Wv = Wbf + 5 * 16384;
    bq = bqp; bk_ = bkp; bv = bvp;
    SQ = SQp; BK = BKp; BV = BVp;
  }
  const int b = g0 / T;
  const int tl0 = g0 - b * T;
  const int NIT = T / 16, NKT = T / 32;

#pragma unroll
  for (int r = 0; r < 8; ++r) {
    int i4 = tid + 256 * r;                      // 2048 float4 = 64x128
    int t = i4 >> 5, k4 = (i4 & 31) * 4;
    float4 v = *(const float4*)&X[(size_t)(g0 + t) * 128 + k4];
    us4 p;
    p.x = f2bf(v.x); p.y = f2bf(v.y); p.z = f2bf(v.z); p.w = f2bf(v.w);
    *(us4*)&xL[t * 136 + k4] = p;
  }
  __syncthreads();

  const int lane = tid & 63, wave = tid >> 6;
  const int lo = lane & 15, hi = lane >> 4;
  const int d0 = wave * 32;

  f32x4 aQ[4][2], aK[4][2], aV[4][2];
#pragma unroll
  for (int a = 0; a < 4; ++a)
#pragma unroll
    for (int s = 0; s < 2; ++s)
#pragma unroll
      for (int r = 0; r < 4; ++r) { aQ[a][s][r] = 0.f; aK[a][s][r] = 0.f; aV[a][s][r] = 0.f; }

#pragma unroll
  for (int kt = 0; kt < 128; kt += 32) {
    bf16x8 bQ[2], bK[2], bV[2];
#pragma unroll
    for (int s = 0; s < 2; ++s) {
      size_t roff = (size_t)(d0 + s * 16 + lo) * 128 + kt + hi * 8;
      bQ[s] = *(const bf16x8*)&Wq[roff];
      bK[s] = *(const bf16x8*)&Wk[roff];
      bV[s] = *(const bf16x8*)&Wv[roff];
    }
#pragma unroll
    for (int a = 0; a < 4; ++a) {
      bf16x8 af = *(const bf16x8*)&xL[(a * 16 + lo) * 136 + kt + hi * 8];
#pragma unroll
      for (int s = 0; s < 2; ++s) {
        aQ[a][s] = __builtin_amdgcn_mfma_f32_16x16x32_bf16(af, bQ[s], aQ[a][s], 0, 0, 0);
        aK[a][s] = __builtin_amdgcn_mfma_f32_16x16x32_bf16(af, bK[s], aK[a][s], 0, 0, 0);
        aV[a][s] = __builtin_amdgcn_mfma_f32_16x16x32_bf16(af, bV[s], aV[a][s], 0, 0, 0);
      }
    }
  }

  // ---- sigQ -> C-frag order: CF[b][it][dt][lane][r]
#pragma unroll
  for (int s = 0; s < 2; ++s) {
    int dt = (d0 >> 4) + s;
    float bb = bq[d0 + s * 16 + lo];
#pragma unroll
    for (int a = 0; a < 4; ++a) {
      int it = (tl0 >> 4) + a;
      us4 v;
#pragma unroll
      for (int r = 0; r < 4; ++r) {
        float q = aQ[a][s][r] + bb;
        v[r] = f2bf(1.f / (1.f + __expf(-q)));
      }
      ((us4*)SQ)[(((size_t)b * NIT + it) * 8 + dt) * 64 + lane] = v;
    }
  }

  // ---- eK/eKV -> B-frag order: BF[b][kt][dt][lane_f][c], c=(hi&1)*4+r
#pragma unroll
  for (int s = 0; s < 2; ++s) {
    int dt = (d0 >> 4) + s;
    float bbk = bk_[d0 + s * 16 + lo], bbv = bv[d0 + s * 16 + lo];
#pragma unroll
    for (int a = 0; a < 4; ++a) {
      int kt = (tl0 >> 5) + (a >> 1);
      int lane_f = ((a & 1) * 2 + (hi >> 1)) * 16 + lo;
      us4 vk, vv;
#pragma unroll
      for (int r = 0; r < 4; ++r) {
        int tg = g0 + a * 16 + hi * 4 + r;      // global key-token index
        int mk = mask[tg];
        float ek = mk ? __expf(aK[a][s][r] + bbk) : 0.f;
        float ekv = ek * (aV[a][s][r] + bbv);
        vk[r] = f2bf(ek);
        vv[r] = f2bf(ekv);
      }
      size_t q4 = ((((size_t)b * NKT + kt) * 8 + dt) * 64 + lane_f) * 2 + (hi & 1);
      ((us4*)BK)[q4] = vk;
      ((us4*)BV)[q4] = vv;
    }
  }
}

// ---------------------------------------------------------------------------
// aft_all (512 thr, 8 waves, LDS-staged, role-split):
//   Block tile 128i x 128d. Wave (role=w>>2, ih=(w>>1)&1, dh=w&1) computes
//   64i x 64d of num (role 0, B=eKV) or den (role 1, B=eK): 64 AGPR acc.
//   Per kt-32 step: stage A 8 KB + eKV 8 KB + eK 8 KB ONCE per block via
//   24 gld16 (3/wave), then 8 ds_read_b128 + 16 MFMA per wave (m97 ratio).
//   Global traffic: 188 B/MFMA (was ~500 in-register-direct) -> TA unbound.
//   Epilogue: den -> sL (bf16), num waves form Y -> yL, all 8 waves
//   Z = Y@Wp^T + bias (16i x 128d each), masked row-max, encoded atomicMax.
//   Blocks [0,128): drug (2 i-blocks x 64 b, NKT=32); [128,640): protein
//   (8 i-blocks x 64 b, NKT=8).
// ---------------------------------------------------------------------------
__global__ __launch_bounds__(512, 4) void aft_all(
    const unsigned short* __restrict__ AFd, const unsigned short* __restrict__ AFp,
    const unsigned short* __restrict__ SQd, const unsigned short* __restrict__ BKd,
    const unsigned short* __restrict__ BVd,
    const unsigned short* __restrict__ SQp, const unsigned short* __restrict__ BKp,
    const unsigned short* __restrict__ BVp,
    const int* __restrict__ smask, const int* __restrict__ pmask,
    const unsigned short* __restrict__ Wbf,
    const float* __restrict__ bpd, const float* __restrict__ bpp,
    unsigned int* __restrict__ outEnc) {
  // sL: staging (24 chunks x 1024 B = 24 KB) / denL (32 KB) union; yL: 34.8 KB
  __shared__ unsigned short smem[16384 + 128 * 136];
  unsigned short* sL = smem;
  unsigned short* yL = smem + 16384;

  const int blk = blockIdx.x;
  const unsigned short *AF, *BK, *BV, *SQ, *Wp;
  const float* bp;
  const int* msk;
  unsigned int* oEnc;
  int b, i0, NKT, NIT;
  if (blk < 128) {  // drug queries over protein keys; blk = iblk*64 + b
    b = blk & 63; i0 = (blk >> 6) * 128; NKT = 32; NIT = 16;
    AF = AFd; BK = BKp; BV = BVp; SQ = SQd;
    Wp = Wbf + 6 * 16384; bp = bpd; msk = smask + b * 256 + i0; oEnc = outEnc;
  } else {          // protein queries over drug keys
    int k = blk - 128;
    b = k & 63; i0 = (k >> 6) * 128; NKT = 8; NIT = 64;
    AF = AFp; BK = BKd; BV = BVd; SQ = SQp;
    Wp = Wbf + 7 * 16384; bp = bpp; msk = pmask + b * 1024 + i0; oEnc = outEnc + 8192;
  }

  const int tid = threadIdx.x, lane = tid & 63, w = tid >> 6;
  const int lo = lane & 15, hi = lane >> 4;
  const int role = w >> 2;                 // 0 = num (eKV), 1 = den (eK)
  const int ih = (w >> 1) & 1, dh = w & 1;
  const int itg0 = i0 >> 4;                // block's first i-tile (8 tiles)
  const int dt0 = dh * 4;

  const unsigned short* BVb = BV + (size_t)b * NKT * 8 * 512;
  const unsigned short* BKb = BK + (size_t)b * NKT * 8 * 512;

  f32x4 acc[4][4];
#pragma unroll
  for (int a = 0; a < 4; ++a)
#pragma unroll
    for (int n = 0; n < 4; ++n)
#pragma unroll
      for (int r = 0; r < 4; ++r) acc[a][n][r] = 0.f;

  for (int kt = 0; kt < NKT; ++kt) {
    __syncthreads();   // previous iteration's ds_reads complete
    // stage 24 chunks (A it 0..7 -> c 0..7; eKV dt -> 8..15; eK dt -> 16..23)
#pragma unroll
    for (int j = 0; j < 3; ++j) {
      int c = w * 3 + j;                   // wave-uniform
      const unsigned short* src;
      if (c < 8)       src = AF + (size_t)((itg0 + c) * NKT + kt) * 512;
      else if (c < 16) src = BVb + (size_t)(kt * 8 + (c - 8)) * 512;
      else             src = BKb + (size_t)(kt * 8 + (c - 16)) * 512;
      gld16(src + lane * 8, sL + c * 512);
    }
    __syncthreads();   // vmcnt(0) drain: staged data visible
    bf16x8 af[4], bb[4];
#pragma unroll
    for (int a = 0; a < 4; ++a)
      af[a] = *(const bf16x8*)&sL[(ih * 4 + a) * 512 + lane * 8];
#pragma unroll
    for (int n = 0; n < 4; ++n)
      bb[n] = *(const bf16x8*)&sL[(8 + role * 8 + dt0 + n) * 512 + lane * 8];
#pragma unroll
    for (int a = 0; a < 4; ++a)
#pragma unroll
      for (int n = 0; n < 4; ++n)
        acc[a][n] = __builtin_amdgcn_mfma_f32_16x16x32_bf16(af[a], bb[n], acc[a][n], 0, 0, 0);
  }

  // ---- exchange: den waves publish den (bf16, us4 per (a,n), coalesced)
  __syncthreads();
  if (role == 1) {
#pragma unroll
    for (int a = 0; a < 4; ++a)
#pragma unroll
      for (int n = 0; n < 4; ++n) {
        us4 v;
#pragma unroll
        for (int r = 0; r < 4; ++r) v[r] = f2bf(acc[a][n][r]);
        ((us4*)sL)[((((ih * 2 + dh) * 4 + a) * 4 + n)) * 64 + lane] = v;
      }
  }
  __syncthreads();

  // ---- num waves: Y = sig(Q)*num/den -> yL bf16 [128 i][136 stride]
  if (role == 0) {
#pragma unroll
    for (int a = 0; a < 4; ++a)
#pragma unroll
      for (int n = 0; n < 4; ++n) {
        us4 dv = ((const us4*)sL)[((((ih * 2 + dh) * 4 + a) * 4 + n)) * 64 + lane];
        us4 q = ((const us4*)SQ)[(((size_t)b * NIT + itg0 + ih * 4 + a) * 8 + dt0 + n) * 64 + lane];
        int iL = ih * 64 + a * 16 + hi * 4;
        int d = dh * 64 + n * 16 + lo;
#pragma unroll
        for (int r = 0; r < 4; ++r) {
          float y = bf2f(q[r]) * __fdividef(acc[a][n][r], bf2f(dv[r]));
          yL[(iL + r) * 136 + d] = f2bf(y);
        }
      }
  }
  __syncthreads();

  // ---- Z = Y @ Wp^T (K=128): 8 waves, 16i x 128d each
  const int wi2 = w * 16;
  f32x4 aZ[8];
#pragma unroll
  for (int n = 0; n < 8; ++n)
#pragma unroll
    for (int r = 0; r < 4; ++r) aZ[n][r] = 0.f;

#pragma unroll
  for (int kt = 0; kt < 128; kt += 32) {
    bf16x8 af2 = *(const bf16x8*)&yL[(wi2 + lo) * 136 + kt + hi * 8];
#pragma unroll
    for (int n = 0; n < 8; ++n) {
      bf16x8 bw = *(const bf16x8*)&Wp[(size_t)(n * 16 + lo) * 128 + kt + hi * 8];
      aZ[n] = __builtin_amdgcn_mfma_f32_16x16x32_bf16(af2, bw, aZ[n], 0, 0, 0);
    }
  }

#pragma unroll
  for (int n = 0; n < 8; ++n) {
    int d = n * 16 + lo;
    float bbia = bp[d];
    float m = NEGV;
#pragma unroll
    for (int r = 0; r < 4; ++r) {
      int iL = wi2 + hi * 4 + r;
      float z = aZ[n][r] + bbia;
      m = msk[iL] ? fmaxf(m, z) : m;
    }
    m = fmaxf(m, __shfl_xor(m, 16, 64));
    m = fmaxf(m, __shfl_xor(m, 32, 64));
    if (hi == 0) {
      unsigned bits = __float_as_uint(m);
      unsigned key = (bits & 0x80000000u) ? ~bits : (bits | 0x80000000u);
      atomicMax(&oEnc[b * 128 + d], key);
    }
  }
}

// ---------------------------------------------------------------------------
__global__ void out_decode(unsigned int* o) {
  int i = blockIdx.x * 256 + threadIdx.x;
  unsigned k = o[i];
  unsigned bits = (k & 0x80000000u) ? (k ^ 0x80000000u) : ~k;
  ((float*)o)[i] = __uint_as_float(bits);
}

// ---------------------------------------------------------------------------
extern "C" void kernel_launch(void* const* d_in, const int* in_sizes, int n_in,
                              void* d_out, int out_size, void* d_ws, size_t ws_size,
                              hipStream_t stream) {
  const float* smiles = (const float*)d_in[0];
  const float* prot   = (const float*)d_in[1];
  const int* smask = (const int*)d_in[2];
  const int* pmask = (const int*)d_in[3];
  const float* pos_bias = (const float*)d_in[4];
  const float* Wqd = (const float*)d_in[5];  const float* bqd = (const float*)d_in[6];
  const float* Wkp = (const float*)d_in[7];  const float* bkp = (const float*)d_in[8];
  const float* Wvp = (const float*)d_in[9];  const float* bvp = (const float*)d_in[10];
  const float* Wqp = (const float*)d_in[11]; const float* bqp = (const float*)d_in[12];
  const float* Wkd = (const float*)d_in[13]; const float* bkd = (const float*)d_in[14];
  const float* Wvd = (const float*)d_in[15]; const float* bvd = (const float*)d_in[16];
  const float* Wpd = (const float*)d_in[17]; const float* bpd = (const float*)d_in[18];
  const float* Wpp = (const float*)d_in[19]; const float* bpp = (const float*)d_in[20];

  // Workspace (unsigned short units)
  unsigned short* u = (unsigned short*)d_ws;
  unsigned short* BKp_  = u;                  // 64*32*8*512 = 8,388,608
  unsigned short* BVp_  = BKp_ + 8388608;     // 8,388,608
  unsigned short* BKd_  = BVp_ + 8388608;     // 64*8*8*512 = 2,097,152
  unsigned short* BVd_  = BKd_ + 2097152;     // 2,097,152
  unsigned short* SQd_  = BVd_ + 2097152;     // 64*16*8*256 = 2,097,152
  unsigned short* SQp_  = SQd_ + 2097152;     // 64*64*8*256 = 8,388,608
  unsigned short* epb_  = SQp_ + 8388608;     // 262,144
  unsigned short* epbT_ = epb_ + 262144;      // 262,144
  unsigned short* AFd_  = epbT_ + 262144;     // 16*32*512 = 262,144
  unsigned short* AFp_  = AFd_ + 262144;      // 64*8*512 = 262,144
  unsigned short* Wbf   = AFp_ + 262144;      // 8 * 16,384
  // Wbf order: [Wqd, Wkd, Wvd, Wqp, Wkp, Wvp, Wpd, Wpp]

  prep_kernel<<<448, 256, 0, stream>>>(Wqd, Wkd, Wvd, Wqp, Wkp, Wvp, Wpd, Wpp,
                                       Wbf, pos_bias, epb_, epbT_,
                                       (unsigned int*)d_out);

  proj3_all<<<1536, 256, 0, stream>>>(smiles, prot, smask, pmask, Wbf,
                                      bqd, bkd, bvd, bqp, bkp, bvp,
                                      epb_, epbT_, AFd_, AFp_,
                                      SQd_, BKd_, BVd_, SQp_, BKp_, BVp_);

  aft_all<<<640, 512, 0, stream>>>(AFd_, AFp_, SQd_, BKd_, BVd_,
                                   SQp_, BKp_, BVp_, smask, pmask, Wbf,
                                   bpd, bpp, (unsigned int*)d_out);

  out_decode<<<64, 256, 0, stream>>>((unsigned int*)d_out);
}

// Round 11
// 187.454 us; speedup vs baseline: 1.0665x; 1.0665x over previous
//
#include <hip/hip_runtime.h>
#include <hip/hip_bf16.h>
#include <cstdint>
#include <cstddef>

#define NEGV -1e9f

typedef __bf16 bf16x8 __attribute__((ext_vector_type(8)));
typedef float f32x4 __attribute__((ext_vector_type(4)));
typedef unsigned short us4 __attribute__((ext_vector_type(4)));
typedef unsigned short us8 __attribute__((ext_vector_type(8)));

__device__ __forceinline__ unsigned short f2bf(float f) {
  unsigned int u = __float_as_uint(f);
  u += 0x7fffu + ((u >> 16) & 1u);   // round-to-nearest-even
  return (unsigned short)(u >> 16);
}
__device__ __forceinline__ float bf2f(unsigned short u) {
  return __uint_as_float(((unsigned)u) << 16);
}
// packed f32x2 -> bf16x2 (v_cvt_pk_bf16_f32 on gfx950): a -> low, b -> high
__device__ __forceinline__ unsigned int f2bf2(float a, float b) {
  __hip_bfloat162 h = __float22bfloat162_rn(make_float2(a, b));
  unsigned int u;
  __builtin_memcpy(&u, &h, 4);
  return u;
}
__device__ __forceinline__ us4 pk4(float a, float b, float c, float d) {
  uint2 u = make_uint2(f2bf2(a, b), f2bf2(c, d));
  us4 r;
  __builtin_memcpy(&r, &u, 8);
  return r;
}

// ===========================================================================
// Fragment-order layouts (16x16x32 MFMA, lane = hi*16+lo, hi=lane>>4, lo=lane&15):
//  A-frag table  AF[it][kt][lane][c]  : value(i = it*16+lo, j = kt*32+hi*8+c)
//  B-frag table  BF[b][kt][dt][lane][c]: value(d = dt*16+lo, j = kt*32+hi*8+c)
//  C-frag table  CF[b][it][dt][lane][r]: value(i = it*16+hi*4+r, d = dt*16+lo)
// ===========================================================================

// ---------------------------------------------------------------------------
// prep: out_init (0..63) + wcvt 8 weights (64..191) + plain epb/epbT (192..447)
// ---------------------------------------------------------------------------
__global__ void prep_kernel(const float* __restrict__ w0, const float* __restrict__ w1,
                            const float* __restrict__ w2, const float* __restrict__ w3,
                            const float* __restrict__ w4, const float* __restrict__ w5,
                            const float* __restrict__ w6, const float* __restrict__ w7,
                            unsigned short* __restrict__ Wbf,
                            const float* __restrict__ pb,
                            unsigned short* __restrict__ epb,
                            unsigned short* __restrict__ epbT,
                            unsigned int* __restrict__ outEnc) {
  __shared__ unsigned short t[32][33];
  const int blk = blockIdx.x, tid = threadIdx.x;
  if (blk < 64) {
    outEnc[blk * 256 + tid] = 0u;
    return;
  }
  if (blk < 192) {
    const float* Ws[8] = {w0, w1, w2, w3, w4, w5, w6, w7};
    int idx = (blk - 64) * 256 + tid;        // 0..32767 float4s
    int mat = idx >> 12, off = idx & 4095;
    float4 v = *(const float4*)&Ws[mat][(size_t)off * 4];
    *(us4*)&Wbf[(size_t)mat * 16384 + (size_t)off * 4] = pk4(v.x, v.y, v.z, v.w);
    return;
  }
  const int bid = blk - 192;
  const int j0 = (bid & 31) * 32, i0 = (bid >> 5) * 32;
  const int tx = tid & 31, ty = tid >> 5;
#pragma unroll
  for (int r = 0; r < 4; ++r) {
    int i = i0 + ty + r * 8;
    unsigned short u = f2bf(__expf(pb[(size_t)i * 1024 + j0 + tx]));
    epb[(size_t)i * 1024 + j0 + tx] = u;
    t[ty + r * 8][tx] = u;
  }
  __syncthreads();
#pragma unroll
  for (int r = 0; r < 4; ++r)
    epbT[(size_t)(j0 + ty + r * 8) * 256 + i0 + tx] = t[tx][ty + r * 8];
}

// ---------------------------------------------------------------------------
// proj3_all (256 thr, R6-proven form, packed-cvt): blocks [0,256) drug,
// [256,1280) protein projections; [1280,1536) pack epb/epbT into A-frag tables.
// Writes sigQ in C-frag order, eK/eKV in B-frag order, from MFMA accumulators.
// ---------------------------------------------------------------------------
__global__ __launch_bounds__(256) void proj3_all(
    const float* __restrict__ smiles, const float* __restrict__ prot,
    const int* __restrict__ smask, const int* __restrict__ pmask,
    const unsigned short* __restrict__ Wbf,
    const float* __restrict__ bqd, const float* __restrict__ bkd, const float* __restrict__ bvd,
    const float* __restrict__ bqp, const float* __restrict__ bkp, const float* __restrict__ bvp,
    const unsigned short* __restrict__ epb, const unsigned short* __restrict__ epbT,
    unsigned short* __restrict__ AFd, unsigned short* __restrict__ AFp,
    unsigned short* __restrict__ SQd, unsigned short* __restrict__ BKd,
    unsigned short* __restrict__ BVd,
    unsigned short* __restrict__ SQp, unsigned short* __restrict__ BKp,
    unsigned short* __restrict__ BVp) {
  const int tid = threadIdx.x;

  if (blockIdx.x >= 1280) {   // ---- A-frag packing ----
    int sid = (blockIdx.x - 1280) * 256 + tid;   // 0..65535 us8-slots
    if (sid < 32768) {        // drug-query A: [it<16][kt<32][lane][8]
      int lane = sid & 63, kt = (sid >> 6) & 31, it = sid >> 11;
      int i = it * 16 + (lane & 15), j = kt * 32 + (lane >> 4) * 8;
      *(us8*)&AFd[(size_t)sid * 8] = *(const us8*)&epb[(size_t)i * 1024 + j];
    } else {                  // protein-query A: [it<64][kt<8][lane][8]
      int s2 = sid - 32768;
      int lane = s2 & 63, kt = (s2 >> 6) & 7, it = s2 >> 9;
      int i = it * 16 + (lane & 15), j = kt * 32 + (lane >> 4) * 8;
      *(us8*)&AFp[(size_t)s2 * 8] = *(const us8*)&epbT[(size_t)i * 256 + j];
    }
    return;
  }

  __shared__ unsigned short xL[64 * 136];   // 17408 B

  const float* X; const int* mask;
  const unsigned short *Wq, *Wk, *Wv;
  const float *bq, *bk_, *bv;
  unsigned short *SQ, *BK, *BV;
  int T, g0;
  if (blockIdx.x < 256) {
    X = smiles; mask = smask; T = 256; g0 = blockIdx.x * 64;
    Wq = Wbf; Wk = Wbf + 16384; Wv = Wbf + 32768;
    bq = bqd; bk_ = bkd; bv = bvd;
    SQ = SQd; BK = BKd; BV = BVd;
  } else {
    X = prot; mask = pmask; T = 1024; g0 = (blockIdx.x - 256) * 64;
    Wq = Wbf + 3 * 16384; Wk = Wbf + 4 * 16384; Wv = Wbf + 5 * 16384;
    bq = bqp; bk_ = bkp; bv = bvp;
    SQ = SQp; BK = BKp; BV = BVp;
  }
  const int b = g0 / T;
  const int tl0 = g0 - b * T;
  const int NIT = T / 16, NKT = T / 32;

#pragma unroll
  for (int r = 0; r < 8; ++r) {
    int i4 = tid + 256 * r;                      // 2048 float4 = 64x128
    int t = i4 >> 5, k4 = (i4 & 31) * 4;
    float4 v = *(const float4*)&X[(size_t)(g0 + t) * 128 + k4];
    *(us4*)&xL[t * 136 + k4] = pk4(v.x, v.y, v.z, v.w);
  }
  __syncthreads();

  const int lane = tid & 63, wave = tid >> 6;
  const int lo = lane & 15, hi = lane >> 4;
  const int d0 = wave * 32;

  f32x4 aQ[4][2], aK[4][2], aV[4][2];
#pragma unroll
  for (int a = 0; a < 4; ++a)
#pragma unroll
    for (int s = 0; s < 2; ++s)
#pragma unroll
      for (int r = 0; r < 4; ++r) { aQ[a][s][r] = 0.f; aK[a][s][r] = 0.f; aV[a][s][r] = 0.f; }

#pragma unroll
  for (int kt = 0; kt < 128; kt += 32) {
    bf16x8 bQ[2], bK[2], bV[2];
#pragma unroll
    for (int s = 0; s < 2; ++s) {
      size_t roff = (size_t)(d0 + s * 16 + lo) * 128 + kt + hi * 8;
      bQ[s] = *(const bf16x8*)&Wq[roff];
      bK[s] = *(const bf16x8*)&Wk[roff];
      bV[s] = *(const bf16x8*)&Wv[roff];
    }
#pragma unroll
    for (int a = 0; a < 4; ++a) {
      bf16x8 af = *(const bf16x8*)&xL[(a * 16 + lo) * 136 + kt + hi * 8];
#pragma unroll
      for (int s = 0; s < 2; ++s) {
        aQ[a][s] = __builtin_amdgcn_mfma_f32_16x16x32_bf16(af, bQ[s], aQ[a][s], 0, 0, 0);
        aK[a][s] = __builtin_amdgcn_mfma_f32_16x16x32_bf16(af, bK[s], aK[a][s], 0, 0, 0);
        aV[a][s] = __builtin_amdgcn_mfma_f32_16x16x32_bf16(af, bV[s], aV[a][s], 0, 0, 0);
      }
    }
  }

  // ---- sigQ -> C-frag order: CF[b][it][dt][lane][r]
#pragma unroll
  for (int s = 0; s < 2; ++s) {
    int dt = (d0 >> 4) + s;
    float bb = bq[d0 + s * 16 + lo];
#pragma unroll
    for (int a = 0; a < 4; ++a) {
      int it = (tl0 >> 4) + a;
      float y0 = 1.f / (1.f + __expf(-(aQ[a][s][0] + bb)));
      float y1 = 1.f / (1.f + __expf(-(aQ[a][s][1] + bb)));
      float y2 = 1.f / (1.f + __expf(-(aQ[a][s][2] + bb)));
      float y3 = 1.f / (1.f + __expf(-(aQ[a][s][3] + bb)));
      ((us4*)SQ)[(((size_t)b * NIT + it) * 8 + dt) * 64 + lane] = pk4(y0, y1, y2, y3);
    }
  }

  // ---- eK/eKV -> B-frag order: BF[b][kt][dt][lane_f][c], c=(hi&1)*4+r
#pragma unroll
  for (int s = 0; s < 2; ++s) {
    int dt = (d0 >> 4) + s;
    float bbk = bk_[d0 + s * 16 + lo], bbv = bv[d0 + s * 16 + lo];
#pragma unroll
    for (int a = 0; a < 4; ++a) {
      int kt = (tl0 >> 5) + (a >> 1);
      int lane_f = ((a & 1) * 2 + (hi >> 1)) * 16 + lo;
      float ek[4], ekv[4];
#pragma unroll
      for (int r = 0; r < 4; ++r) {
        int tg = g0 + a * 16 + hi * 4 + r;      // global key-token index
        int mk = mask[tg];
        ek[r] = mk ? __expf(aK[a][s][r] + bbk) : 0.f;
        ekv[r] = ek[r] * (aV[a][s][r] + bbv);
      }
      size_t q4 = ((((size_t)b * NKT + kt) * 8 + dt) * 64 + lane_f) * 2 + (hi & 1);
      ((us4*)BK)[q4] = pk4(ek[0], ek[1], ek[2], ek[3]);
      ((us4*)BV)[q4] = pk4(ekv[0], ekv[1], ekv[2], ekv[3]);
    }
  }
}

// ---------------------------------------------------------------------------
// aft_all (512 thr, 8 waves, role-split num/den — R7 measured-best form):
//   Waves 0-3: num (64i x 64d, 64 AGPR); waves 4-7: den (same tile).
//   Barrier-free main loop over fragment-packed operands (no LDS).
//   Exchange: den -> LDS (bf16, coalesced us4), num-waves form Y -> yL,
//   then all 8 waves: Z = Y@Wp^T + bias (32i x 64d each), masked row-max,
//   order-encoded atomicMax.
// ---------------------------------------------------------------------------
__global__ __launch_bounds__(512, 4) void aft_all(
    const unsigned short* __restrict__ AFd, const unsigned short* __restrict__ AFp,
    const unsigned short* __restrict__ SQd, const unsigned short* __restrict__ BKd,
    const unsigned short* __restrict__ BVd,
    const unsigned short* __restrict__ SQp, const unsigned short* __restrict__ BKp,
    const unsigned short* __restrict__ BVp,
    const int* __restrict__ smask, const int* __restrict__ pmask,
    const unsigned short* __restrict__ Wbf,
    const float* __restrict__ bpd, const float* __restrict__ bpp,
    unsigned int* __restrict__ outEnc) {
  __shared__ unsigned short smem[16384 + 128 * 136];  // denL (32KB) + yL (34KB)
  unsigned short* denL = smem;
  unsigned short* yL = smem + 16384;

  const int blk = blockIdx.x;
  const unsigned short *AF, *BK, *BV, *SQ, *Wp;
  const float* bp;
  const int* msk;
  unsigned int* oEnc;
  int b, i0, NKT, NIT;
  if (blk < 128) {  // drug queries over protein keys; blk = itile*64 + b
    b = blk & 63; i0 = (blk >> 6) * 128; NKT = 32; NIT = 16;
    AF = AFd; BK = BKp; BV = BVp; SQ = SQd;
    Wp = Wbf + 6 * 16384; bp = bpd; msk = smask + b * 256 + i0; oEnc = outEnc;
  } else {          // protein queries over drug keys
    int k = blk - 128;
    b = k & 63; i0 = (k >> 6) * 128; NKT = 8; NIT = 64;
    AF = AFp; BK = BKd; BV = BVd; SQ = SQp;
    Wp = Wbf + 7 * 16384; bp = bpp; msk = pmask + b * 1024 + i0; oEnc = outEnc + 8192;
  }

  const int tid = threadIdx.x, lane = tid & 63, w = tid >> 6;
  const int lo = lane & 15, hi = lane >> 4;
  const int wv = w & 3;                    // tile index within role
  const int wi = (wv >> 1) * 64, wd = (wv & 1) * 64;
  const int it0 = (i0 + wi) >> 4;          // i-tile base (local to side)
  const int dt0 = wd >> 4;                 // d-tile base

  // num-waves (w<4) multiply by eKV; den-waves (w>=4) by eK
  const unsigned short* Bb = ((w < 4) ? BV : BK) + (size_t)b * NKT * 8 * 64 * 8;

  f32x4 acc[4][4];
#pragma unroll
  for (int a = 0; a < 4; ++a)
#pragma unroll
    for (int n = 0; n < 4; ++n)
#pragma unroll
      for (int r = 0; r < 4; ++r) acc[a][n][r] = 0.f;

#pragma unroll 2
  for (int kt = 0; kt < NKT; ++kt) {
    bf16x8 af[4];
#pragma unroll
    for (int a = 0; a < 4; ++a)
      af[a] = *(const bf16x8*)&AF[(((size_t)(it0 + a) * NKT + kt) * 64 + lane) * 8];
    bf16x8 bb[4];
#pragma unroll
    for (int n = 0; n < 4; ++n)
      bb[n] = *(const bf16x8*)&Bb[(((size_t)kt * 8 + dt0 + n) * 64 + lane) * 8];
#pragma unroll
    for (int a = 0; a < 4; ++a)
#pragma unroll
      for (int n = 0; n < 4; ++n)
        acc[a][n] = __builtin_amdgcn_mfma_f32_16x16x32_bf16(af[a], bb[n], acc[a][n], 0, 0, 0);
  }

  // ---- exchange: den-waves publish den (bf16, fragment-linear, coalesced)
  if (w >= 4) {
#pragma unroll
    for (int a = 0; a < 4; ++a)
#pragma unroll
      for (int n = 0; n < 4; ++n)
        ((us4*)denL)[(wv * 16 + a * 4 + n) * 64 + lane] =
            pk4(acc[a][n][0], acc[a][n][1], acc[a][n][2], acc[a][n][3]);
  }
  __syncthreads();

  // ---- num-waves: Y = sig(Q)*num/den -> yL bf16 [128 i][136 stride]
  if (w < 4) {
#pragma unroll
    for (int a = 0; a < 4; ++a)
#pragma unroll
      for (int n = 0; n < 4; ++n) {
        us4 dv = ((const us4*)denL)[(wv * 16 + a * 4 + n) * 64 + lane];
        us4 q = ((const us4*)SQ)[(((size_t)b * NIT + it0 + a) * 8 + dt0 + n) * 64 + lane];
        int iL = wi + a * 16 + hi * 4;
        int d = wd + n * 16 + lo;
#pragma unroll
        for (int r = 0; r < 4; ++r) {
          float y = bf2f(q[r]) * __fdividef(acc[a][n][r], bf2f(dv[r]));
          yL[(iL + r) * 136 + d] = f2bf(y);
        }
      }
  }
  __syncthreads();

  // ---- Z = Y @ Wp^T (K=128): 8 waves, 32i x 64d each
  const int wi2 = (w & 3) * 32, wd2 = (w >> 2) * 64;
  f32x4 aZ[2][4];
#pragma unroll
  for (int a = 0; a < 2; ++a)
#pragma unroll
    for (int n = 0; n < 4; ++n)
#pragma unroll
      for (int r = 0; r < 4; ++r) aZ[a][n][r] = 0.f;

#pragma unroll
  for (int kt = 0; kt < 128; kt += 32) {
    bf16x8 bw[4];
#pragma unroll
    for (int n = 0; n < 4; ++n)
      bw[n] = *(const bf16x8*)&Wp[(size_t)(wd2 + n * 16 + lo) * 128 + kt + hi * 8];
#pragma unroll
    for (int a = 0; a < 2; ++a) {
      bf16x8 af = *(const bf16x8*)&yL[(wi2 + a * 16 + lo) * 136 + kt + hi * 8];
#pragma unroll
      for (int n = 0; n < 4; ++n)
        aZ[a][n] = __builtin_amdgcn_mfma_f32_16x16x32_bf16(af, bw[n], aZ[a][n], 0, 0, 0);
    }
  }

#pragma unroll
  for (int n = 0; n < 4; ++n) {
    int d = wd2 + n * 16 + lo;
    float bb = bp[d];
    float m = NEGV;
#pragma unroll
    for (int a = 0; a < 2; ++a)
#pragma unroll
      for (int r = 0; r < 4; ++r) {
        int iL = wi2 + a * 16 + hi * 4 + r;
        float z = aZ[a][n][r] + bb;
        m = msk[iL] ? fmaxf(m, z) : m;
      }
    m = fmaxf(m, __shfl_xor(m, 16, 64));
    m = fmaxf(m, __shfl_xor(m, 32, 64));
    if (hi == 0) {
      unsigned bits = __float_as_uint(m);
      unsigned key = (bits & 0x80000000u) ? ~bits : (bits | 0x80000000u);
      atomicMax(&oEnc[b * 128 + d], key);
    }
  }
}

// ---------------------------------------------------------------------------
__global__ void out_decode(unsigned int* o) {
  int i = blockIdx.x * 256 + threadIdx.x;
  unsigned k = o[i];
  unsigned bits = (k & 0x80000000u) ? (k ^ 0x80000000u) : ~k;
  ((float*)o)[i] = __uint_as_float(bits);
}

// ---------------------------------------------------------------------------
extern "C" void kernel_launch(void* const* d_in, const int* in_sizes, int n_in,
                              void* d_out, int out_size, void* d_ws, size_t ws_size,
                              hipStream_t stream) {
  const float* smiles = (const float*)d_in[0];
  const float* prot   = (const float*)d_in[1];
  const int* smask = (const int*)d_in[2];
  const int* pmask = (const int*)d_in[3];
  const float* pos_bias = (const float*)d_in[4];
  const float* Wqd = (const float*)d_in[5];  const float* bqd = (const float*)d_in[6];
  const float* Wkp = (const float*)d_in[7];  const float* bkp = (const float*)d_in[8];
  const float* Wvp = (const float*)d_in[9];  const float* bvp = (const float*)d_in[10];
  const float* Wqp = (const float*)d_in[11]; const float* bqp = (const float*)d_in[12];
  const float* Wkd = (const float*)d_in[13]; const float* bkd = (const float*)d_in[14];
  const float* Wvd = (const float*)d_in[15]; const float* bvd = (const float*)d_in[16];
  const float* Wpd = (const float*)d_in[17]; const float* bpd = (const float*)d_in[18];
  const float* Wpp = (const float*)d_in[19]; const float* bpp = (const float*)d_in[20];

  // Workspace (unsigned short units)
  unsigned short* u = (unsigned short*)d_ws;
  unsigned short* BKp_  = u;                  // 64*32*8*512 = 8,388,608
  unsigned short* BVp_  = BKp_ + 8388608;     // 8,388,608
  unsigned short* BKd_  = BVp_ + 8388608;     // 64*8*8*512 = 2,097,152
  unsigned short* BVd_  = BKd_ + 2097152;     // 2,097,152
  unsigned short* SQd_  = BVd_ + 2097152;     // 64*16*8*256 = 2,097,152
  unsigned short* SQp_  = SQd_ + 2097152;     // 64*64*8*256 = 8,388,608
  unsigned short* epb_  = SQp_ + 8388608;     // 262,144
  unsigned short* epbT_ = epb_ + 262144;      // 262,144
  unsigned short* AFd_  = epbT_ + 262144;     // 16*32*512 = 262,144
  unsigned short* AFp_  = AFd_ + 262144;      // 64*8*512 = 262,144
  unsigned short* Wbf   = AFp_ + 262144;      // 8 * 16,384
  // Wbf order: [Wqd, Wkd, Wvd, Wqp, Wkp, Wvp, Wpd, Wpp]

  prep_kernel<<<448, 256, 0, stream>>>(Wqd, Wkd, Wvd, Wqp, Wkp, Wvp, Wpd, Wpp,
                                       Wbf, pos_bias, epb_, epbT_,
                                       (unsigned int*)d_out);

  proj3_all<<<1536, 256, 0, stream>>>(smiles, prot, smask, pmask, Wbf,
                                      bqd, bkd, bvd, bqp, bkp, bvp,
                                      epb_, epbT_, AFd_, AFp_,
                                      SQd_, BKd_, BVd_, SQp_, BKp_, BVp_);

  aft_all<<<640, 512, 0, stream>>>(AFd_, AFp_, SQd_, BKd_, BVd_,
                                   SQp_, BKp_, BVp_, smask, pmask, Wbf,
                                   bpd, bpp, (unsigned int*)d_out);

  out_decode<<<64, 256, 0, stream>>>((unsigned int*)d_out);
}